// Round 6
// baseline (233.653 us; speedup 1.0000x reference)
//
#include <hip/hip_runtime.h>
#include <hip/hip_bf16.h>

typedef unsigned int uint;
typedef unsigned short ushort;

#define Bn 128
#define Ln 512
#define Hn 512
#define Tn 24
#define START_TAG 22
#define STOP_TAG 23
#define NCH 32  // chunks per batch
#define CHL 16  // timesteps per chunk

using frag_ab = __attribute__((ext_vector_type(8))) short;
using frag_cd = __attribute__((ext_vector_type(4))) float;
union ABU { frag_ab f; uint u[4]; };

// pack two f32 into one u32 of 2 bf16 (truncation) via v_perm
#define PACKW(x, y) \
  __builtin_amdgcn_perm(__float_as_uint(y), __float_as_uint(x), 0x07060302u)
#define MFMA16 __builtin_amdgcn_mfma_f32_16x16x32_bf16

__device__ __forceinline__ float bf2f(ushort v) {
  return __uint_as_float(((uint)v) << 16);
}
__device__ __forceinline__ ushort f2bf_rne(float x) {
  uint u = __float_as_uint(x);
  return (ushort)((u + 0x7FFFu + ((u >> 16) & 1u)) >> 16);
}
__device__ __forceinline__ float rlf(float v, int l) {
  return __int_as_float(__builtin_amdgcn_readlane(__float_as_int(v), l));
}
__device__ __forceinline__ float rfl(float v) {
  return __int_as_float(__builtin_amdgcn_readfirstlane(__float_as_int(v)));
}
__device__ __forceinline__ uint bperm(int addr, uint v) {
  return (uint)__builtin_amdgcn_ds_bpermute(addr, (int)v);
}

// ============ Kernel 0: W f32 -> bf16 (once per launch) ====================
__global__ __launch_bounds__(256) void wconv(const float* __restrict__ W,
                                             ushort* __restrict__ Wbf) {
  int i = blockIdx.x * 256 + threadIdx.x;
  if (i < Tn * Hn) Wbf[i] = f2bf_rne(W[i]);
}

// ============ Fused kernel: emission GEMM + chunk chain ====================
// 4 waves/block; wave w owns chunk bid*4+w = (batch b, 16 timesteps).
// Phase 1: ee = exp(feat·W^T + bias) via MFMA -> LDS (f32, 32-col padded).
// Phase 2: P <- diag(ee_t)·(E·P): MFMA with CONSTANT A-frags of E, then
// row-scale D by ee_t. D->B relayout via 16 ds_bpermute (verified in R5).
__global__ __launch_bounds__(256, 4) void fused_kernel(
    const float* __restrict__ feat, const ushort* __restrict__ Wbf,
    const float* __restrict__ bias, const float* __restrict__ trans,
    const int* __restrict__ lengths, ushort* __restrict__ G,
    float* __restrict__ Rc, float* __restrict__ u0buf) {
  __shared__ float ee[4][CHL][32];
  const int wv = threadIdx.x >> 6, l = threadIdx.x & 63;
  const int ct = l & 15, g = l >> 4;
  const int chunk = blockIdx.x * 4 + wv;
  const int b = chunk >> 5, c = chunk & 31;

  // ---------------- phase 1: emission GEMM ----------------
  const float* fp = feat + (size_t)(chunk * CHL + ct) * Hn + 8 * g;
  const ushort* wp0 = Wbf + ct * Hn + 8 * g;
  const ushort* wp1 = Wbf + (16 + (ct & 7)) * Hn + 8 * g;
  frag_cd acc0 = {0.f, 0.f, 0.f, 0.f}, acc1 = {0.f, 0.f, 0.f, 0.f};
#pragma unroll 4
  for (int kk = 0; kk < 16; ++kk) {
    float4 fa = *(const float4*)(fp + kk * 32);
    float4 fb = *(const float4*)(fp + kk * 32 + 4);
    frag_ab b0 = *(const frag_ab*)(wp0 + kk * 32);
    frag_ab b1 = *(const frag_ab*)(wp1 + kk * 32);
    ABU A;
    A.u[0] = PACKW(fa.x, fa.y);
    A.u[1] = PACKW(fa.z, fa.w);
    A.u[2] = PACKW(fb.x, fb.y);
    A.u[3] = PACKW(fb.z, fb.w);
    acc0 = MFMA16(A.f, b0, acc0, 0, 0, 0);
    acc1 = MFMA16(A.f, b1, acc1, 0, 0, 0);
  }
  const float bs0 = bias[ct];
  const float bs1 = bias[16 + (ct & 7)];
#pragma unroll
  for (int r = 0; r < 4; ++r) {
    ee[wv][4 * g + r][ct] = __expf(acc0[r] + bs0);
    if (ct < 8) {
      ee[wv][4 * g + r][16 + ct] = __expf(acc1[r] + bs1);
      ee[wv][4 * g + r][24 + ct] = 0.f;  // zero-pad cols 24..31
    }
  }
  __syncthreads();
  if (c == 0 && l < Tn) u0buf[b * Tn + l] = ee[wv][0][l];

  // ---------------- constant A-frags of E = exp(trans) ----------------
  // A-frag lane (ct,g): A0c = E[ct][8g+i]; A1c = E[16+ct][8g+i] (0 if >=24)
  ABU A0c, A1c;
#pragma unroll
  for (int h = 0; h < 4; ++h) {
    int k0 = 8 * g + 2 * h, k1 = k0 + 1;
    float e00 = (k0 < Tn) ? __expf(trans[ct * Tn + k0]) : 0.f;
    float e01 = (k1 < Tn) ? __expf(trans[ct * Tn + k1]) : 0.f;
    A0c.u[h] = PACKW(e00, e01);
    float e10 = (k0 < Tn && ct < 8) ? __expf(trans[(16 + ct) * Tn + k0]) : 0.f;
    float e11 = (k1 < Tn && ct < 8) ? __expf(trans[(16 + ct) * Tn + k1]) : 0.f;
    A1c.u[h] = PACKW(e10, e11);
  }

  // ---------------- phase 2: chunk chain ----------------
  const int len = lengths[b];
  const int lo = (c == 0) ? 1 : 0;
  int hi = len - c * CHL;
  if (hi > CHL) hi = CHL;

  // P = I (32x32) in D-frag form: quadrant (m,n), row 16m+4g+r, col 16n+ct
  frag_cd D00, D01, D10, D11;
#pragma unroll
  for (int r = 0; r < 4; ++r) {
    float dv = (4 * g + r == ct) ? 1.f : 0.f;
    D00[r] = dv; D11[r] = dv; D01[r] = 0.f; D10[r] = 0.f;
  }

  float R = 0.f;
  const int addr0 = (ct + 32 * (g & 1)) * 4;  // src lane ct+32*(g&1)
  const int addr1 = addr0 + 64;               // src lane +16
  const bool mhi = (g >= 2);

#define RENORMF()                                                       \
  do {                                                                  \
    float ref = fmaxf(fmaxf(D00[0], D00[1]), fmaxf(D00[2], D00[3]));    \
    ref = rfl(ref);                                                     \
    int ebx = ((__float_as_int(ref) >> 23) & 255) - 127;                \
    float sc = __int_as_float((uint)(127 - ebx) << 23);                 \
    _Pragma("unroll") for (int r = 0; r < 4; ++r) {                     \
      D00[r] *= sc; D01[r] *= sc; D10[r] *= sc; D11[r] *= sc;           \
    }                                                                   \
    R += (float)ebx * 0.6931471805599453f;                              \
  } while (0)

  int stepc = 0;
  for (int lt = lo; lt < hi; ++lt) {
    // pack current state quadrants to bf16 pairs (elems {0,1},{2,3})
    uint p000 = PACKW(D00[0], D00[1]), p001 = PACKW(D00[2], D00[3]);
    uint p010 = PACKW(D01[0], D01[1]), p011 = PACKW(D01[2], D01[3]);
    uint p100 = PACKW(D10[0], D10[1]), p101 = PACKW(D10[2], D10[3]);
    uint p110 = PACKW(D11[0], D11[1]), p111 = PACKW(D11[2], D11[3]);
    // redistribute D -> B-frags (same pattern verified in R5)
    ABU Bf0, Bf1;
    {
      uint a0 = bperm(addr0, p000), b0 = bperm(addr0, p100);
      uint a1 = bperm(addr0, p001), b1 = bperm(addr0, p101);
      uint a2 = bperm(addr1, p000), b2 = bperm(addr1, p100);
      uint a3 = bperm(addr1, p001), b3 = bperm(addr1, p101);
      Bf0.u[0] = mhi ? b0 : a0;
      Bf0.u[1] = mhi ? b1 : a1;
      Bf0.u[2] = mhi ? b2 : a2;
      Bf0.u[3] = mhi ? b3 : a3;
      a0 = bperm(addr0, p010); b0 = bperm(addr0, p110);
      a1 = bperm(addr0, p011); b1 = bperm(addr0, p111);
      a2 = bperm(addr1, p010); b2 = bperm(addr1, p110);
      a3 = bperm(addr1, p011); b3 = bperm(addr1, p111);
      Bf1.u[0] = mhi ? b0 : a0;
      Bf1.u[1] = mhi ? b1 : a1;
      Bf1.u[2] = mhi ? b2 : a2;
      Bf1.u[3] = mhi ? b3 : a3;
    }
    // N = E * P (constant A), then row-scale by ee_t: P' = diag(ee_t)*N
    frag_cd z = {0.f, 0.f, 0.f, 0.f};
    frag_cd N00 = MFMA16(A0c.f, Bf0.f, z, 0, 0, 0);
    frag_cd N01 = MFMA16(A0c.f, Bf1.f, z, 0, 0, 0);
    frag_cd N10 = MFMA16(A1c.f, Bf0.f, z, 0, 0, 0);
    frag_cd N11 = MFMA16(A1c.f, Bf1.f, z, 0, 0, 0);
    float4 s0 = *(const float4*)(&ee[wv][lt][4 * g]);       // rows 4g+r
    float4 s1 = *(const float4*)(&ee[wv][lt][16 + 4 * g]);  // rows 16+4g+r
    D00[0] = N00[0] * s0.x; D00[1] = N00[1] * s0.y;
    D00[2] = N00[2] * s0.z; D00[3] = N00[3] * s0.w;
    D01[0] = N01[0] * s0.x; D01[1] = N01[1] * s0.y;
    D01[2] = N01[2] * s0.z; D01[3] = N01[3] * s0.w;
    D10[0] = N10[0] * s1.x; D10[1] = N10[1] * s1.y;
    D10[2] = N10[2] * s1.z; D10[3] = N10[3] * s1.w;
    D11[0] = N11[0] * s1.x; D11[1] = N11[1] * s1.y;
    D11[2] = N11[2] * s1.z; D11[3] = N11[3] * s1.w;
    if ((++stepc & 3) == 0) RENORMF();
  }
  RENORMF();  // bound entries before bf16 store

  // store chunk product column-major bf16: Gc[col*32 + row]
  ushort* Gc = G + (size_t)chunk * 1024;
  uint2 w2;
  w2.x = PACKW(D00[0], D00[1]); w2.y = PACKW(D00[2], D00[3]);
  *(uint2*)(Gc + ct * 32 + 4 * g) = w2;
  w2.x = PACKW(D01[0], D01[1]); w2.y = PACKW(D01[2], D01[3]);
  *(uint2*)(Gc + (16 + ct) * 32 + 4 * g) = w2;
  w2.x = PACKW(D10[0], D10[1]); w2.y = PACKW(D10[2], D10[3]);
  *(uint2*)(Gc + ct * 32 + 16 + 4 * g) = w2;
  w2.x = PACKW(D11[0], D11[1]); w2.y = PACKW(D11[2], D11[3]);
  *(uint2*)(Gc + (16 + ct) * 32 + 16 + 4 * g) = w2;
  if (l == 0) Rc[chunk] = R;
}

// ============ passB: fold 32 chunk matrices + terminal LSE =================
__global__ __launch_bounds__(64) void passB(
    const float* __restrict__ trans, const ushort* __restrict__ G,
    const float* __restrict__ Rc, const float* __restrict__ u0buf,
    float* __restrict__ out) {
  const int b = blockIdx.x;
  const int j = threadIdx.x;
  const bool act = j < Tn;
  const int jj = act ? j : 0;

  float v = act ? u0buf[b * Tn + jj] * __expf(trans[jj * Tn + START_TAG]) : 0.f;
  float R = 0.f;
  const ushort* Gb = G + (size_t)b * (NCH * 1024);

#pragma unroll 1
  for (int c = 0; c < NCH; ++c) {
    const ushort* Gc = Gb + c * 1024;
    float p[24];
#pragma unroll
    for (int k = 0; k < 24; ++k) p[k] = bf2f(Gc[k * 32 + jj]);
    float s = 0.f;
#pragma unroll
    for (int k = 0; k < 24; ++k) s = fmaf(p[k], rlf(v, k), s);
    v = act ? s : 0.f;
    R += Rc[b * NCH + c];
    float ref = rfl(v);  // lane 0 = tag 0, generically nonzero
    int ebx = ((__float_as_int(ref) >> 23) & 255) - 127;
    v *= __int_as_float((uint)(127 - ebx) << 23);
    R += (float)ebx * 0.6931471805599453f;
  }

  float term = act ? v * __expf(trans[STOP_TAG * Tn + jj]) : 0.f;
  term += __shfl_xor(term, 1, 64);
  term += __shfl_xor(term, 2, 64);
  term += __shfl_xor(term, 4, 64);
  term += __shfl_xor(term, 8, 64);
  term += __shfl_xor(term, 16, 64);
  term += __shfl_xor(term, 32, 64);
  if (j == 0) out[b] = R + logf(term);
}

// ============ launch =======================================================
extern "C" void kernel_launch(void* const* d_in, const int* in_sizes, int n_in,
                              void* d_out, int out_size, void* d_ws,
                              size_t ws_size, hipStream_t stream) {
  const float* feat = (const float*)d_in[0];   // [B, L, H]
  const float* W = (const float*)d_in[1];      // [T, H]
  const float* bias = (const float*)d_in[2];   // [T]
  const float* trans = (const float*)d_in[3];  // [T, T]
  const int* lengths = (const int*)d_in[4];    // [B]
  float* out = (float*)d_out;                  // [B]

  ushort* G = (ushort*)d_ws;                       // 8,388,608 B
  float* Rc = (float*)((char*)d_ws + 8388608);     //    16,384 B
  float* u0buf = (float*)((char*)d_ws + 8404992);  //    12,288 B
  ushort* Wbf = (ushort*)((char*)d_ws + 8417280);  //    24,576 B

  wconv<<<48, 256, 0, stream>>>(W, Wbf);
  fused_kernel<<<Bn * NCH / 4, 256, 0, stream>>>(feat, Wbf, bias, trans,
                                                 lengths, G, Rc, u0buf);
  passB<<<Bn, 64, 0, stream>>>(trans, G, Rc, u0buf, out);
}